// Round 18
// baseline (379.966 us; speedup 1.0000x reference)
//
#include <hip/hip_runtime.h>

typedef unsigned short u16;
typedef _Float16 f16x8 __attribute__((ext_vector_type(8)));
typedef short bf16x8 __attribute__((ext_vector_type(8)));
typedef float f32x16 __attribute__((ext_vector_type(16)));
typedef unsigned int u32x4 __attribute__((ext_vector_type(4)));
typedef unsigned int u32x2 __attribute__((ext_vector_type(2)));

#define LOG2E 1.44269504088896340736f

static __device__ __forceinline__ u16 f2h(float f){
  union { _Float16 h; u16 u; } v; v.h = (_Float16)f; return v.u;
}
static __device__ __forceinline__ u16 f2bf(float f){
  union { float f; unsigned u; } v; v.f = f;
  return (u16)((v.u + 0x7fffu + ((v.u >> 16) & 1u)) >> 16);
}
static __device__ __forceinline__ unsigned pk2bf(float lo, float hi){
  unsigned r; asm("v_cvt_pk_bf16_f32 %0, %1, %2" : "=v"(r) : "v"(lo), "v"(hi)); return r;
}
static __device__ __forceinline__ float ex2(float x){
#if __has_builtin(__builtin_amdgcn_exp2f)
  return __builtin_amdgcn_exp2f(x);
#else
  return exp2f(x);
#endif
}
#define PSWAP(a, b) asm("v_permlane32_swap_b32 %0, %1" : "+v"(a), "+v"(b))

typedef __attribute__((address_space(3))) unsigned int lds_u32;
typedef __attribute__((address_space(1))) const unsigned int glob_u32;
#define GLL(gp, lp) __builtin_amdgcn_global_load_lds((glob_u32*)(gp), (lds_u32*)(lp), 16, 0, 0)

// B=8, C=512, N=4096, MID=64
// ---- kernel 0: w16[640][512] f16 = [Wd(512) ; LOG2E*Wb(64) ; Wc(64)] ----
__global__ __launch_bounds__(256) void k_wcvt(const float* __restrict__ wb, const float* __restrict__ wc,
                                              const float* __restrict__ wd, u16* __restrict__ w16){
  int row = blockIdx.x, t = threadIdx.x;
  const float* src; float sc;
  if (row < 512)      { src = wd + (size_t)row * 512;        sc = 1.0f;  }
  else if (row < 576) { src = wb + (size_t)(row - 512) * 512; sc = LOG2E; }
  else                { src = wc + (size_t)(row - 576) * 512; sc = 1.0f;  }
  float2 v = *(const float2*)(src + t * 2);
  unsigned pk = (unsigned)f2h(v.x * sc) | ((unsigned)f2h(v.y * sc) << 16);
  *(unsigned*)(w16 + (size_t)row * 512 + t * 2) = pk;
}

// ---- kernel 1: fused projections (x-stage double-buffered through registers) ----
__global__ __launch_bounds__(512, 1) void k_fused(const float* __restrict__ x, const u16* __restrict__ w16,
                                                  u16* __restrict__ qkb, u16* __restrict__ vtb){
  __shared__ u16 ltmp[64 * 140];   // [c][n] f16, stride 140 u16
  __shared__ u16 lx[128 * 68];     // [n][c] f16, stride 68 u16
  __shared__ u16 lw[640 * 68];     // [row][c] f16, stride 68 u16; reused as qkl in epilogue
  int bx = blockIdx.x;
  int b = bx >> 5, nb = bx & 31;
  int t = threadIdx.x, w = t >> 6, l = t & 63, hi = l >> 5, ln = l & 31;
  int i = w & 1, j = w >> 1;
  size_t b4096 = (size_t)b * 4096;
  f32x16 acc[5][2] = {};
  int cS = t >> 3, ncS = t & 7;
  int nT = t & 127, q4 = t >> 7;
  const float* xbase = x + ((size_t)(b * 512 + cS)) * 4096 + nb * 128 + ncS * 16;
  float4 xpre[4];
#pragma unroll
  for (int g = 0; g < 4; ++g) xpre[g] = *(const float4*)(xbase + g * 4);
  for (int kt = 0; kt < 8; ++kt) {
    int c0 = kt * 64;
    {
      u16* d = &ltmp[cS * 140 + ncS * 16];
#pragma unroll
      for (int g = 0; g < 4; ++g) {
        float4 v = xpre[g];
        unsigned lo = (unsigned)f2h(v.x) | ((unsigned)f2h(v.y) << 16);
        unsigned h2 = (unsigned)f2h(v.z) | ((unsigned)f2h(v.w) << 16);
        *(u32x2*)(d + g * 4) = u32x2{lo, h2};
      }
    }
#pragma unroll
    for (int k10 = 0; k10 < 10; ++k10) {
      int slot = t + 512 * k10;
      int row = slot >> 3, ch8 = slot & 7;
      u32x4 wv = *(const u32x4*)(w16 + (size_t)row * 512 + c0 + ch8 * 8);
      u16* d = &lw[row * 68 + ch8 * 8];
      *(u32x2*)d       = u32x2{wv[0], wv[1]};
      *(u32x2*)(d + 4) = u32x2{wv[2], wv[3]};
    }
    __syncthreads();
    if (kt < 7) {
      const float* xp = xbase + (size_t)(kt + 1) * 64 * 4096;
#pragma unroll
      for (int g = 0; g < 4; ++g) xpre[g] = *(const float4*)(xp + g * 4);
    }
    {
      u16 tmp[16];
#pragma unroll
      for (int k = 0; k < 16; ++k) tmp[k] = ltmp[(q4 * 16 + k) * 140 + nT];
      u16* d = &lx[nT * 68 + q4 * 16];
#pragma unroll
      for (int g = 0; g < 4; ++g) {
        unsigned lo = (unsigned)tmp[g * 4]     | ((unsigned)tmp[g * 4 + 1] << 16);
        unsigned h2 = (unsigned)tmp[g * 4 + 2] | ((unsigned)tmp[g * 4 + 3] << 16);
        *(u32x2*)(d + g * 4) = u32x2{lo, h2};
      }
    }
    __syncthreads();
#pragma unroll
    for (int cc = 0; cc < 4; ++cc) {
      union { u32x2 d[2]; f16x8 v; } bf[2];
#pragma unroll
      for (int u = 0; u < 2; ++u) {
        const u16* p = &lx[(i * 64 + u * 32 + ln) * 68 + cc * 16 + hi * 8];
        bf[u].d[0] = *(const u32x2*)p; bf[u].d[1] = *(const u32x2*)(p + 4);
      }
#pragma unroll
      for (int s = 0; s < 5; ++s) {
        union { u32x2 d[2]; f16x8 v; } af;
        const u16* p = &lw[(j * 160 + s * 32 + ln) * 68 + cc * 16 + hi * 8];
        af.d[0] = *(const u32x2*)p; af.d[1] = *(const u32x2*)(p + 4);
#pragma unroll
        for (int u = 0; u < 2; ++u)
          acc[s][u] = __builtin_amdgcn_mfma_f32_32x32x16_f16(af.v, bf[u].v, acc[s][u], 0, 0, 0);
      }
    }
    __syncthreads();
  }
#pragma unroll
  for (int s = 0; s < 5; ++s) {
    int rt = j * 160 + s * 32;
    if (rt < 512) {
#pragma unroll
      for (int u = 0; u < 2; ++u) {
        int n = nb * 128 + i * 64 + u * 32 + ln;
#pragma unroll
        for (int r = 0; r < 16; ++r) {
          int o = rt + (r & 3) + 8 * (r >> 2) + 4 * hi;
          vtb[((size_t)(b * 512 + o)) * 4096 + n] = f2bf(acc[s][u][r]);
        }
      }
    }
  }
  u16* qkl = lw;
  if (j == 3) {
#pragma unroll
    for (int s = 1; s < 5; ++s) {
      int mbase = (s - 1) * 32;
#pragma unroll
      for (int u = 0; u < 2; ++u) {
        int nl = i * 64 + u * 32 + ln;
#pragma unroll
        for (int r = 0; r < 16; ++r) {
          int m = mbase + (r & 3) + 8 * (r >> 2) + 4 * hi;
          qkl[nl * 132 + m] = f2h(acc[s][u][r]);
        }
      }
    }
  }
  __syncthreads();
  {
    int n2 = t >> 2, ch = t & 3;
    u16* dst = qkb + (b4096 + nb * 128 + n2) * 128 + ch * 32;
#pragma unroll
    for (int g = 0; g < 4; ++g) {
      u32x2 d0 = *(const u32x2*)(&qkl[n2 * 132 + ch * 32 + g * 8]);
      u32x2 d1 = *(const u32x2*)(&qkl[n2 * 132 + ch * 32 + g * 8 + 4]);
      *(u32x4*)(dst + g * 8) = u32x4{d0[0], d0[1], d1[0], d1[1]};
    }
  }
}

// ------------- kernel 2: flash attention, q-sub 2 at 1 wave/SIMD (512-reg budget) -------------
// 4 waves x 64 q (two 32-q subs); o-chunk 256; KV tile 64. GLL staging (linear LDS dest,
// inverse-swizzled source, XOR-swizzled b128 reads), double buffer, 1 barrier/iter.
// Each K-frag LDS read feeds 2 q-subs (from regs); each V-frag read feeds 2 MFMAs
// -> LDS reads per CU-iter HALVED vs R17 (160 vs 320 b128).
__global__ __launch_bounds__(256, 1) void k_attn2(const u16* __restrict__ qk, const u16* __restrict__ vt,
                                                  const float* __restrict__ x, const float* __restrict__ gamma,
                                                  float* __restrict__ out){
  __shared__ char smem[81920];   // buf[i] at i*40960: K [64][128B] @+0, V [256][128B] @+8192
  int bx = blockIdx.x;
  int orig = (bx & 7) * 32 + (bx >> 3);
  int combo = orig >> 4, qt = orig & 15;
  int b = combo >> 1, oc2 = combo & 1;
  int obase = oc2 * 256;
  int t = threadIdx.x, w = t >> 6, l = t & 63, hi = l >> 5, ln = l & 31;
  size_t b4096 = (size_t)b * 4096;
  // Q fragments for both q-subs (log2e folded in k_fused)
  f16x8 qf0[4], qf1[4];
  {
    const u16* q0 = qk + (b4096 + qt * 256 + w * 64 + ln) * 128;
    const u16* q1 = q0 + 32 * 128;
#pragma unroll
    for (int ch = 0; ch < 4; ++ch) {
      qf0[ch] = *(const f16x8*)(q0 + ch * 16 + hi * 8);
      qf1[ch] = *(const f16x8*)(q1 + ch * 16 + hi * 8);
    }
  }
  // XOR-swizzled b128 read offsets (R8/R17-proven)
  unsigned rb[4];
#pragma unroll
  for (int cc = 0; cc < 4; ++cc)
    rb[cc] = (unsigned)(ln * 128 + (((cc << 5) | (hi << 4)) ^ ((ln & 7) << 4)));
  // GLL source: slot s = i*256 + t -> row = i*32 + (t>>3), chunk = ((t&7)^((t>>3)&7))*8
  // (32 = 0 mod 8, so the same per-thread chunk works for every issue i)
  int row = t >> 3;
  int ch2 = ((t & 7) ^ (row & 7)) * 8;
  const u16* gK = qk + (b4096 + row) * 128 + 64 + ch2;                 // + i*4096 per issue
  const u16* gV = vt + ((size_t)(b * 512 + obase + row)) * 4096 + ch2; // + i*131072 per issue
  unsigned ldsW = (unsigned)(w * 1024);   // wave base within each 4096B issue-slab
  // prologue: tile 0 -> buf0 (2 K issues + 8 V issues)
  {
    char* nb_ = smem;
    GLL(gK,           nb_ + ldsW);
    GLL(gK + 4096,    nb_ + 4096 + ldsW);
#pragma unroll
    for (int i = 0; i < 8; ++i)
      GLL(gV + i * 131072, nb_ + 8192 + i * 4096 + ldsW);
  }
  gK += 8192; gV += 64;
  f32x16 acc0[8] = {}, acc1[8] = {};
  float lacc0 = 0.0f, lacc1 = 0.0f;
  for (int kt = 0; kt < 64; ++kt) {
    __syncthreads();   // drains GLL -> buf[kt&1] ready; prior reads of buf[(kt+1)&1] done
    char* bufp = smem + (kt & 1) * 40960;
    if (kt < 63) {     // issue next tile into other buffer; flies during this iter's compute
      char* nb_ = smem + ((kt + 1) & 1) * 40960;
      GLL(gK,           nb_ + ldsW);
      GLL(gK + 4096,    nb_ + 4096 + ldsW);
#pragma unroll
      for (int i = 0; i < 8; ++i)
        GLL(gV + i * 131072, nb_ + 8192 + i * 4096 + ldsW);
      gK += 8192; gV += 64;
    }
    // QK both q-subs: each K-frag read feeds 2 MFMAs
    f32x16 s00 = {}, s01 = {}, s10 = {}, s11 = {};
    __builtin_amdgcn_s_setprio(1);
#pragma unroll
    for (int cc = 0; cc < 4; ++cc) {
      f16x8 k0 = *(const f16x8*)(bufp + rb[cc]);
      f16x8 k1 = *(const f16x8*)(bufp + 4096 + rb[cc]);
      s00 = __builtin_amdgcn_mfma_f32_32x32x16_f16(k0, qf0[cc], s00, 0, 0, 0);
      s10 = __builtin_amdgcn_mfma_f32_32x32x16_f16(k0, qf1[cc], s10, 0, 0, 0);
      s01 = __builtin_amdgcn_mfma_f32_32x32x16_f16(k1, qf0[cc], s01, 0, 0, 0);
      s11 = __builtin_amdgcn_mfma_f32_32x32x16_f16(k1, qf1[cc], s11, 0, 0, 0);
    }
    __builtin_amdgcn_s_setprio(0);
    // 4 kc-blocks: {exp2 x16 (both q-subs), sums, pack pa0/pa1, 8 vb reads x 2 MFMA}
    float psum0 = 0.0f, psum1 = 0.0f;
#pragma unroll
    for (int blk = 0; blk < 4; ++blk) {
      const int base = (blk & 1) * 8;
      f32x16& sva = (blk < 2) ? s00 : s01;
      f32x16& svb = (blk < 2) ? s10 : s11;
      float e0[8], e1[8];
#pragma unroll
      for (int jj = 0; jj < 8; ++jj) e0[jj] = ex2(sva[base + jj]);
#pragma unroll
      for (int jj = 0; jj < 8; ++jj) e1[jj] = ex2(svb[base + jj]);
      psum0 += ((e0[0] + e0[1]) + (e0[2] + e0[3])) + ((e0[4] + e0[5]) + (e0[6] + e0[7]));
      psum1 += ((e1[0] + e1[1]) + (e1[2] + e1[3])) + ((e1[4] + e1[5]) + (e1[6] + e1[7]));
      unsigned ca[4], cb[4];
      ca[0] = pk2bf(e0[0], e0[1]); ca[1] = pk2bf(e0[2], e0[3]);
      ca[2] = pk2bf(e0[4], e0[5]); ca[3] = pk2bf(e0[6], e0[7]);
      cb[0] = pk2bf(e1[0], e1[1]); cb[1] = pk2bf(e1[2], e1[3]);
      cb[2] = pk2bf(e1[4], e1[5]); cb[3] = pk2bf(e1[6], e1[7]);
      PSWAP(ca[0], ca[2]); PSWAP(ca[1], ca[3]);
      PSWAP(cb[0], cb[2]); PSWAP(cb[1], cb[3]);
      union U8 { unsigned u[4]; bf16x8 v; } pa0, pa1;
      pa0.u[0] = ca[0]; pa0.u[1] = ca[1]; pa0.u[2] = ca[2]; pa0.u[3] = ca[3];
      pa1.u[0] = cb[0]; pa1.u[1] = cb[1]; pa1.u[2] = cb[2]; pa1.u[3] = cb[3];
      const char* pv = bufp + 8192 + rb[blk];
      __builtin_amdgcn_s_setprio(1);
#pragma unroll
      for (int ot = 0; ot < 8; ++ot) {
        bf16x8 vb = *(const bf16x8*)(pv + ot * 4096);
        acc0[ot] = __builtin_amdgcn_mfma_f32_32x32x16_bf16(pa0.v, vb, acc0[ot], 0, 0, 0);
        acc1[ot] = __builtin_amdgcn_mfma_f32_32x32x16_bf16(pa1.v, vb, acc1[ot], 0, 0, 0);
      }
      __builtin_amdgcn_s_setprio(0);
    }
    lacc0 += psum0; lacc1 += psum1;
  }
  // epilogue: per-q-sub scale gamma/l; transpose 32x32 tiles via per-wave LDS; coalesced store
  float g = gamma[0];
  float l0 = lacc0 + __shfl_xor(lacc0, 32);
  float l1 = lacc1 + __shfl_xor(lacc1, 32);
  float sinv0 = g / l0, sinv1 = g / l1;
  __syncthreads();
  float* tb = (float*)smem + w * 1056;  // 4x4224B = 16896 <= buf0 (last tile was buf1)
#pragma unroll
  for (int qs = 0; qs < 2; ++qs) {
    float sv = qs ? sinv1 : sinv0;
    size_t qcol = (size_t)(qt * 256 + w * 64 + qs * 32 + ln);
#pragma unroll
    for (int ot = 0; ot < 8; ++ot) {
      f32x16& av = qs ? acc1[ot] : acc0[ot];
#pragma unroll
      for (int r = 0; r < 16; ++r) {
        int qr = (r & 3) + 8 * (r >> 2) + 4 * hi;
        tb[ln * 33 + qr] = av[r];
      }
#pragma unroll
      for (int it = 0; it < 16; ++it) {
        int orow = it * 2 + hi;
        float v = tb[orow * 33 + ln];
        size_t gi = (((size_t)(b * 512 + obase + ot * 32 + orow)) << 12) + qcol;
        out[gi] = sv * v + x[gi];
      }
      __syncthreads();
    }
  }
}

extern "C" void kernel_launch(void* const* d_in, const int* in_sizes, int n_in,
                              void* d_out, int out_size, void* d_ws, size_t ws_size,
                              hipStream_t stream) {
  (void)in_sizes; (void)n_in; (void)out_size; (void)ws_size;
  const float* x     = (const float*)d_in[0];
  const float* wb    = (const float*)d_in[1];
  const float* wc    = (const float*)d_in[2];
  const float* wd    = (const float*)d_in[3];
  const float* gamma = (const float*)d_in[4];
  float* out = (float*)d_out;
  char* ws = (char*)d_ws;
  u16* w16 = (u16*)ws;                    // 640 KB: fused weights f16 [640][512]
  u16* qkb = (u16*)(ws + 1048576);        //   8 MB: [B][N][Q(64)|K(64)] f16
  u16* vtb = (u16*)(ws + 9437184);        //  32 MB: V^T bf16 [B][C][N]
  k_wcvt <<<dim3(640), dim3(256), 0, stream>>>(wb, wc, wd, w16);
  k_fused<<<dim3(256), dim3(512), 0, stream>>>(x, w16, qkb, vtb);
  k_attn2<<<dim3(256), dim3(256), 0, stream>>>(qkb, vtb, x, gamma, out);
}

// Round 19
// 218.441 us; speedup vs baseline: 1.7394x; 1.7394x over previous
//
#include <hip/hip_runtime.h>

typedef unsigned short u16;
typedef _Float16 f16x8 __attribute__((ext_vector_type(8)));
typedef short bf16x8 __attribute__((ext_vector_type(8)));
typedef float f32x16 __attribute__((ext_vector_type(16)));
typedef unsigned int u32x4 __attribute__((ext_vector_type(4)));
typedef unsigned int u32x2 __attribute__((ext_vector_type(2)));

#define LOG2E 1.44269504088896340736f

static __device__ __forceinline__ u16 f2h(float f){
  union { _Float16 h; u16 u; } v; v.h = (_Float16)f; return v.u;
}
static __device__ __forceinline__ u16 f2bf(float f){
  union { float f; unsigned u; } v; v.f = f;
  return (u16)((v.u + 0x7fffu + ((v.u >> 16) & 1u)) >> 16);
}
static __device__ __forceinline__ unsigned pk2bf(float lo, float hi){
  unsigned r; asm("v_cvt_pk_bf16_f32 %0, %1, %2" : "=v"(r) : "v"(lo), "v"(hi)); return r;
}
static __device__ __forceinline__ float ex2(float x){
#if __has_builtin(__builtin_amdgcn_exp2f)
  return __builtin_amdgcn_exp2f(x);
#else
  return exp2f(x);
#endif
}
#define PSWAP(a, b) asm("v_permlane32_swap_b32 %0, %1" : "+v"(a), "+v"(b))

typedef __attribute__((address_space(3))) unsigned int lds_u32;
typedef __attribute__((address_space(1))) const unsigned int glob_u32;
#define GLL(gp, lp) __builtin_amdgcn_global_load_lds((glob_u32*)(gp), (lds_u32*)(lp), 16, 0, 0)

// B=8, C=512, N=4096, MID=64
// ---- kernel 0: w16[640][512] f16 = [Wd(512) ; LOG2E*Wb(64) ; Wc(64)] ----
__global__ __launch_bounds__(256) void k_wcvt(const float* __restrict__ wb, const float* __restrict__ wc,
                                              const float* __restrict__ wd, u16* __restrict__ w16){
  int row = blockIdx.x, t = threadIdx.x;
  const float* src; float sc;
  if (row < 512)      { src = wd + (size_t)row * 512;        sc = 1.0f;  }
  else if (row < 576) { src = wb + (size_t)(row - 512) * 512; sc = LOG2E; }
  else                { src = wc + (size_t)(row - 576) * 512; sc = 1.0f;  }
  float2 v = *(const float2*)(src + t * 2);
  unsigned pk = (unsigned)f2h(v.x * sc) | ((unsigned)f2h(v.y * sc) << 16);
  *(unsigned*)(w16 + (size_t)row * 512 + t * 2) = pk;
}

// ---- kernel 1: fused projections (x-stage double-buffered through registers) ----
__global__ __launch_bounds__(512, 1) void k_fused(const float* __restrict__ x, const u16* __restrict__ w16,
                                                  u16* __restrict__ qkb, u16* __restrict__ vtb){
  __shared__ u16 ltmp[64 * 140];   // [c][n] f16, stride 140 u16
  __shared__ u16 lx[128 * 68];     // [n][c] f16, stride 68 u16
  __shared__ u16 lw[640 * 68];     // [row][c] f16, stride 68 u16; reused as qkl in epilogue
  int bx = blockIdx.x;
  int b = bx >> 5, nb = bx & 31;
  int t = threadIdx.x, w = t >> 6, l = t & 63, hi = l >> 5, ln = l & 31;
  int i = w & 1, j = w >> 1;
  size_t b4096 = (size_t)b * 4096;
  f32x16 acc[5][2] = {};
  int cS = t >> 3, ncS = t & 7;
  int nT = t & 127, q4 = t >> 7;
  const float* xbase = x + ((size_t)(b * 512 + cS)) * 4096 + nb * 128 + ncS * 16;
  float4 xpre[4];
#pragma unroll
  for (int g = 0; g < 4; ++g) xpre[g] = *(const float4*)(xbase + g * 4);
  for (int kt = 0; kt < 8; ++kt) {
    int c0 = kt * 64;
    {
      u16* d = &ltmp[cS * 140 + ncS * 16];
#pragma unroll
      for (int g = 0; g < 4; ++g) {
        float4 v = xpre[g];
        unsigned lo = (unsigned)f2h(v.x) | ((unsigned)f2h(v.y) << 16);
        unsigned h2 = (unsigned)f2h(v.z) | ((unsigned)f2h(v.w) << 16);
        *(u32x2*)(d + g * 4) = u32x2{lo, h2};
      }
    }
#pragma unroll
    for (int k10 = 0; k10 < 10; ++k10) {
      int slot = t + 512 * k10;
      int row = slot >> 3, ch8 = slot & 7;
      u32x4 wv = *(const u32x4*)(w16 + (size_t)row * 512 + c0 + ch8 * 8);
      u16* d = &lw[row * 68 + ch8 * 8];
      *(u32x2*)d       = u32x2{wv[0], wv[1]};
      *(u32x2*)(d + 4) = u32x2{wv[2], wv[3]};
    }
    __syncthreads();
    if (kt < 7) {
      const float* xp = xbase + (size_t)(kt + 1) * 64 * 4096;
#pragma unroll
      for (int g = 0; g < 4; ++g) xpre[g] = *(const float4*)(xp + g * 4);
    }
    {
      u16 tmp[16];
#pragma unroll
      for (int k = 0; k < 16; ++k) tmp[k] = ltmp[(q4 * 16 + k) * 140 + nT];
      u16* d = &lx[nT * 68 + q4 * 16];
#pragma unroll
      for (int g = 0; g < 4; ++g) {
        unsigned lo = (unsigned)tmp[g * 4]     | ((unsigned)tmp[g * 4 + 1] << 16);
        unsigned h2 = (unsigned)tmp[g * 4 + 2] | ((unsigned)tmp[g * 4 + 3] << 16);
        *(u32x2*)(d + g * 4) = u32x2{lo, h2};
      }
    }
    __syncthreads();
#pragma unroll
    for (int cc = 0; cc < 4; ++cc) {
      union { u32x2 d[2]; f16x8 v; } bf[2];
#pragma unroll
      for (int u = 0; u < 2; ++u) {
        const u16* p = &lx[(i * 64 + u * 32 + ln) * 68 + cc * 16 + hi * 8];
        bf[u].d[0] = *(const u32x2*)p; bf[u].d[1] = *(const u32x2*)(p + 4);
      }
#pragma unroll
      for (int s = 0; s < 5; ++s) {
        union { u32x2 d[2]; f16x8 v; } af;
        const u16* p = &lw[(j * 160 + s * 32 + ln) * 68 + cc * 16 + hi * 8];
        af.d[0] = *(const u32x2*)p; af.d[1] = *(const u32x2*)(p + 4);
#pragma unroll
        for (int u = 0; u < 2; ++u)
          acc[s][u] = __builtin_amdgcn_mfma_f32_32x32x16_f16(af.v, bf[u].v, acc[s][u], 0, 0, 0);
      }
    }
    __syncthreads();
  }
#pragma unroll
  for (int s = 0; s < 5; ++s) {
    int rt = j * 160 + s * 32;
    if (rt < 512) {
#pragma unroll
      for (int u = 0; u < 2; ++u) {
        int n = nb * 128 + i * 64 + u * 32 + ln;
#pragma unroll
        for (int r = 0; r < 16; ++r) {
          int o = rt + (r & 3) + 8 * (r >> 2) + 4 * hi;
          vtb[((size_t)(b * 512 + o)) * 4096 + n] = f2bf(acc[s][u][r]);
        }
      }
    }
  }
  u16* qkl = lw;
  if (j == 3) {
#pragma unroll
    for (int s = 1; s < 5; ++s) {
      int mbase = (s - 1) * 32;
#pragma unroll
      for (int u = 0; u < 2; ++u) {
        int nl = i * 64 + u * 32 + ln;
#pragma unroll
        for (int r = 0; r < 16; ++r) {
          int m = mbase + (r & 3) + 8 * (r >> 2) + 4 * hi;
          qkl[nl * 132 + m] = f2h(acc[s][u][r]);
        }
      }
    }
  }
  __syncthreads();
  {
    int n2 = t >> 2, ch = t & 3;
    u16* dst = qkb + (b4096 + nb * 128 + n2) * 128 + ch * 32;
#pragma unroll
    for (int g = 0; g < 4; ++g) {
      u32x2 d0 = *(const u32x2*)(&qkl[n2 * 132 + ch * 32 + g * 8]);
      u32x2 d1 = *(const u32x2*)(&qkl[n2 * 132 + ch * 32 + g * 8 + 4]);
      *(u32x4*)(dst + g * 8) = u32x4{d0[0], d0[1], d1[0], d1[1]};
    }
  }
}

// ------------- kernel 2: flash attention, o-chunk 256, GLL staging + XOR-swizzle reads -------------
// P = exp2(S), no max/stats. grid 256 XCD-chunked. 8 waves x 32 q; KV tile 64.
// global_load_lds direct staging (linear LDS rows; inverse-swizzled global source;
// XOR-swizzled b128 reads). Double buffer, 1 barrier/iter.  [best measured: ~188 us]
__global__ __launch_bounds__(512, 1) void k_attn2(const u16* __restrict__ qk, const u16* __restrict__ vt,
                                                  const float* __restrict__ x, const float* __restrict__ gamma,
                                                  float* __restrict__ out){
  __shared__ char smem[81920];   // buf[i] at i*40960: K [64][128B] @+0, V [256][128B] @+8192
  int bx = blockIdx.x;
  int orig = (bx & 7) * 32 + (bx >> 3);
  int combo = orig >> 4, qt = orig & 15;
  int b = combo >> 1, oc2 = combo & 1;
  int obase = oc2 * 256;
  int t = threadIdx.x, w = t >> 6, l = t & 63, hi = l >> 5, ln = l & 31;
  int q = qt * 256 + w * 32 + ln;
  size_t b4096 = (size_t)b * 4096;
  // Q B-fragments (log2e folded in k_fused)
  f16x8 qf[4];
  {
    const u16* qrow = qk + (b4096 + q) * 128;
#pragma unroll
    for (int ch = 0; ch < 4; ++ch) qf[ch] = *(const f16x8*)(qrow + ch * 16 + hi * 8);
  }
  // XOR-swizzled b128 read offsets
  unsigned rb[4];
#pragma unroll
  for (int cc = 0; cc < 4; ++cc)
    rb[cc] = (unsigned)(ln * 128 + (((cc << 5) | (hi << 4)) ^ ((ln & 7) << 4)));
  // GLL source: thread t fills LDS slot (row=t>>3, chunk=t&7); global chunk = (t&7)^(row&7)
  int row = t >> 3;
  int ch2 = ((t & 7) ^ (row & 7)) * 8;
  const u16* gK = qk + (b4096 + row) * 128 + 64 + ch2;
  const u16* gV = vt + ((size_t)(b * 512 + obase + row)) * 4096 + ch2;
  unsigned ldsW = (unsigned)(w * 1024);   // per-wave dest base (lane x 16B implicit)
  // prologue: tile 0 -> buf0
  GLL(gK,            smem + ldsW);
  GLL(gV,            smem + 8192  + ldsW);
  GLL(gV + 262144,   smem + 16384 + ldsW);
  GLL(gV + 524288,   smem + 24576 + ldsW);
  GLL(gV + 786432,   smem + 32768 + ldsW);
  gK += 8192; gV += 64;
  f32x16 acc[8] = {};
  float lacc = 0.0f;
  for (int kt = 0; kt < 64; ++kt) {
    __syncthreads();   // drains GLL -> buf[kt&1] ready; prior reads of buf[(kt+1)&1] done
    char* bufp = smem + (kt & 1) * 40960;
    if (kt < 63) {     // issue next tile into other buffer; flies during this iter's compute
      char* bufn = smem + ((kt + 1) & 1) * 40960;
      GLL(gK,            bufn + ldsW);
      GLL(gV,            bufn + 8192  + ldsW);
      GLL(gV + 262144,   bufn + 16384 + ldsW);
      GLL(gV + 524288,   bufn + 24576 + ldsW);
      GLL(gV + 786432,   bufn + 32768 + ldsW);
      gK += 8192; gV += 64;
    }
    // S^T = K * Q^T : lane holds 32 scores for q=ln (hi splits k 0-31 / 32-63)
    f32x16 s0 = {}, s1 = {};
    __builtin_amdgcn_s_setprio(1);
#pragma unroll
    for (int cc = 0; cc < 4; ++cc) {
      f16x8 k0 = *(const f16x8*)(bufp + rb[cc]);
      f16x8 k1 = *(const f16x8*)(bufp + 4096 + rb[cc]);
      s0 = __builtin_amdgcn_mfma_f32_32x32x16_f16(k0, qf[cc], s0, 0, 0, 0);
      s1 = __builtin_amdgcn_mfma_f32_32x32x16_f16(k1, qf[cc], s1, 0, 0, 0);
    }
    __builtin_amdgcn_s_setprio(0);
    // P = exp2(S), tree row-sum
#pragma unroll
    for (int r = 0; r < 16; ++r) s0[r] = ex2(s0[r]);
#pragma unroll
    for (int r = 0; r < 16; ++r) s1[r] = ex2(s1[r]);
    {
      float p[16];
#pragma unroll
      for (int r = 0; r < 16; ++r) p[r] = s0[r] + s1[r];
#pragma unroll
      for (int d = 8; d >= 1; d >>= 1)
#pragma unroll
        for (int r = 0; r < d; ++r) p[r] += p[r + d];
      lacc += p[0];
    }
    // pack P -> bf16 A-fragments via cvt_pk + permlane32_swap
    unsigned c0[8], c1[8];
#pragma unroll
    for (int ii = 0; ii < 8; ++ii) c0[ii] = pk2bf(s0[2 * ii], s0[2 * ii + 1]);
#pragma unroll
    for (int ii = 0; ii < 8; ++ii) c1[ii] = pk2bf(s1[2 * ii], s1[2 * ii + 1]);
    PSWAP(c0[0], c0[2]); PSWAP(c0[1], c0[3]); PSWAP(c0[4], c0[6]); PSWAP(c0[5], c0[7]);
    PSWAP(c1[0], c1[2]); PSWAP(c1[1], c1[3]); PSWAP(c1[4], c1[6]); PSWAP(c1[5], c1[7]);
    union U8 { unsigned u[4]; bf16x8 v; } pa[4];
#pragma unroll
    for (int jj = 0; jj < 4; ++jj) { pa[0].u[jj] = c0[jj]; pa[1].u[jj] = c0[4 + jj]; pa[2].u[jj] = c1[jj]; pa[3].u[jj] = c1[4 + jj]; }
    // PV
    __builtin_amdgcn_s_setprio(1);
#pragma unroll
    for (int kc = 0; kc < 4; ++kc) {
      const char* pv = bufp + 8192 + rb[kc];
#pragma unroll
      for (int ot = 0; ot < 8; ++ot) {
        bf16x8 vb = *(const bf16x8*)(pv + ot * 4096);
        acc[ot] = __builtin_amdgcn_mfma_f32_32x32x16_bf16(pa[kc].v, vb, acc[ot], 0, 0, 0);
      }
    }
    __builtin_amdgcn_s_setprio(0);
  }
  // epilogue: l per q-row, scale = gamma/l; transpose 32x32 tiles via per-wave LDS; coalesced store
  float l_tot = lacc + __shfl_xor(lacc, 32);
  float sinv = gamma[0] / l_tot;
  __syncthreads();
  float* tb = (float*)smem + w * 1056;  // 8x4224B = 33792 <= buf0 (last tile was buf1)
#pragma unroll
  for (int ot = 0; ot < 8; ++ot) {
#pragma unroll
    for (int r = 0; r < 16; ++r) {
      int qr = (r & 3) + 8 * (r >> 2) + 4 * hi;
      tb[ln * 33 + qr] = acc[ot][r];
    }
#pragma unroll
    for (int it = 0; it < 16; ++it) {
      int orow = it * 2 + hi;
      float v = tb[orow * 33 + ln];
      size_t gi = (((size_t)(b * 512 + obase + ot * 32 + orow)) << 12) + (size_t)(qt * 256 + w * 32 + ln);
      out[gi] = sinv * v + x[gi];
    }
    __syncthreads();
  }
}

extern "C" void kernel_launch(void* const* d_in, const int* in_sizes, int n_in,
                              void* d_out, int out_size, void* d_ws, size_t ws_size,
                              hipStream_t stream) {
  (void)in_sizes; (void)n_in; (void)out_size; (void)ws_size;
  const float* x     = (const float*)d_in[0];
  const float* wb    = (const float*)d_in[1];
  const float* wc    = (const float*)d_in[2];
  const float* wd    = (const float*)d_in[3];
  const float* gamma = (const float*)d_in[4];
  float* out = (float*)d_out;
  char* ws = (char*)d_ws;
  u16* w16 = (u16*)ws;                    // 640 KB: fused weights f16 [640][512]
  u16* qkb = (u16*)(ws + 1048576);        //   8 MB: [B][N][Q(64)|K(64)] f16
  u16* vtb = (u16*)(ws + 9437184);        //  32 MB: V^T bf16 [B][C][N]
  k_wcvt <<<dim3(640), dim3(256), 0, stream>>>(wb, wc, wd, w16);
  k_fused<<<dim3(256), dim3(512), 0, stream>>>(x, w16, qkb, vtb);
  k_attn2<<<dim3(256), dim3(512), 0, stream>>>(qkb, vtb, x, gamma, out);
}